// Round 2
// baseline (6704.864 us; speedup 1.0000x reference)
//
#include <hip/hip_runtime.h>

#define TPB 128

static constexpr int SZ0 = 64 * 128 * 9;    // 73728
static constexpr int SZ1 = 128 * 128 * 9;   // 147456
static constexpr int SZ4 = 128 * 1 * 9;     // 1152
static constexpr int OFF0 = 0;
static constexpr int OFF1 = OFF0 + SZ0;     // 73728
static constexpr int OFF2 = OFF1 + SZ1;
static constexpr int OFF3 = OFF2 + SZ1;
static constexpr int OFF4 = OFF3 + SZ1;     // 516096
// total floats = 517248 -> 2.07 MB in d_ws

// ---------- helpers ----------
// returns 2*tanh(x) = 2 - 4/(exp(2x)+1)
__device__ __forceinline__ float fast_tanh2(float x) {
  float e = __expf(2.0f * x);
  float r = __builtin_amdgcn_rcpf(e + 1.0f);
  return fmaf(-4.0f, r, 2.0f);
}
__device__ __forceinline__ float gelu_exact(float v) {
  return 0.5f * v * (1.0f + erff(v * 0.70710678f));
}

// ---------- weight fusion: layout [p][n][q] ----------
// out[(p*9+n)*Q + q] = tW[(q*P+p)*9+n] * W[q*P+p]
__global__ void fuse_w(const float* __restrict__ W, const float* __restrict__ tW,
                       float* __restrict__ out, int P, int Q, int total) {
  int i = blockIdx.x * 256 + threadIdx.x;
  if (i >= total) return;
  int q = i % Q;
  int r = i / Q;
  int n = r % 9;
  int p = r / 9;
  out[i] = tW[(q * P + p) * 9 + n] * W[q * P + p];
}

// ---------- write m = 2*tanh(h) into LDS (thread-private column) ----------
template <int NV>
__device__ __forceinline__ void write_m(float2* __restrict__ ml,
                                        const float* __restrict__ h, int tid) {
#pragma unroll
  for (int p2 = 0; p2 < NV / 2; ++p2)
    ml[p2 * TPB + tid] = make_float2(fast_tanh2(h[2 * p2]), fast_tanh2(h[2 * p2 + 1]));
}

// ---------- KAN layer: P inputs (m in LDS) -> 128 outputs (h in regs) ----------
template <int P, bool RES>
__device__ __forceinline__ void kan_layer_f32(const float* __restrict__ wf,
                                              const float2* __restrict__ ml,
                                              float (&h)[128], int tid) {
#pragma unroll
  for (int qc = 0; qc < 16; ++qc) {
    float acc[8];
#pragma unroll
    for (int j = 0; j < 8; ++j) acc[j] = 0.0f;
    const float* wq = wf + qc * 8;
#pragma unroll 2
    for (int p2 = 0; p2 < P / 2; ++p2) {
      float2 mm = ml[p2 * TPB + tid];
      float mv[2] = {mm.x, mm.y};
#pragma unroll
      for (int h2 = 0; h2 < 2; ++h2) {
        float m = mv[h2];
        const float* w = wq + (p2 * 2 + h2) * 9 * 128;
        // n = 0: U0 = 1
#pragma unroll
        for (int j = 0; j < 8; ++j) acc[j] += w[j];
        // n = 1: U1 = m
#pragma unroll
        for (int j = 0; j < 8; ++j) acc[j] = fmaf(m, w[128 + j], acc[j]);
        float um2 = 1.0f, um1 = m;
#pragma unroll
        for (int n = 2; n < 9; ++n) {
          float u = fmaf(m, um1, -um2);
          um2 = um1;
          um1 = u;
          const float* wn = w + n * 128;
#pragma unroll
          for (int j = 0; j < 8; ++j) acc[j] = fmaf(u, wn[j], acc[j]);
        }
      }
    }
#pragma unroll
    for (int j = 0; j < 8; ++j) {
      float v = acc[j];
      if (RES) v += h[qc * 8 + j];
      h[qc * 8 + j] = v;
    }
  }
}

// ---------- final layer: 128 -> 1, weights wf4[p*9+n] ----------
__device__ __forceinline__ float kan_layer_out(const float* __restrict__ wf4,
                                               const float2* __restrict__ ml, int tid) {
  float acc = 0.0f;
#pragma unroll 2
  for (int p2 = 0; p2 < 64; ++p2) {
    float2 mm = ml[p2 * TPB + tid];
    float mv[2] = {mm.x, mm.y};
#pragma unroll
    for (int h2 = 0; h2 < 2; ++h2) {
      float m = mv[h2];
      const float* w = wf4 + (p2 * 2 + h2) * 9;
      acc += w[0];
      acc = fmaf(m, w[1], acc);
      float um2 = 1.0f, um1 = m;
#pragma unroll
      for (int n = 2; n < 9; ++n) {
        float u = fmaf(m, um1, -um2);
        um2 = um1;
        um1 = u;
        acc = fmaf(u, w[n], acc);
      }
    }
  }
  return acc;
}

// ---------- main fused kernel ----------
__global__ void __launch_bounds__(TPB, 1)
kan_main(const float* __restrict__ x, const float* __restrict__ Bm,
         const float* __restrict__ wf, float* __restrict__ out) {
  __shared__ float2 ml[64 * TPB];  // 64 KB: per-thread column of up to 64 m-pairs
  int tid = threadIdx.x;
  int b = blockIdx.x * TPB + tid;

  // Fourier features: proj = 2*pi*(x@B); h = [sin(proj), cos(proj)]
  {
    const float4* xp = (const float4*)(x + (size_t)b * 8);
    float4 a = xp[0], c = xp[1];
    float xv[8] = {a.x, a.y, a.z, a.w, c.x, c.y, c.z, c.w};
    float hbuf[64];
#pragma unroll
    for (int j = 0; j < 32; ++j) {
      float r = 0.0f;
#pragma unroll
      for (int k = 0; k < 8; ++k) r = fmaf(xv[k], Bm[k * 32 + j], r);
      float ang = 6.2831855f * r;
      float s, cc;
      sincosf(ang, &s, &cc);
      hbuf[j] = s;
      hbuf[32 + j] = cc;
    }
    write_m<64>(ml, hbuf, tid);
  }

  float h[128];
  kan_layer_f32<64, false>(wf + OFF0, ml, h, tid);
#pragma unroll 1
  for (int l = 0; l < 3; ++l) {
    write_m<128>(ml, h, tid);
    kan_layer_f32<128, true>(wf + OFF1 + l * SZ1, ml, h, tid);
  }
  write_m<128>(ml, h, tid);
  float v = kan_layer_out(wf + OFF4, ml, tid);

  // cheby-gelu, degree 5, T1 = tanh(v) (standard first kind)
  float t = 0.5f * fast_tanh2(v);
  float m2 = t + t;
  float tm2 = 1.0f, tm1 = t;
  float y = gelu_exact(1.0f) + gelu_exact(t);
#pragma unroll
  for (int n = 2; n <= 5; ++n) {
    float tn = fmaf(m2, tm1, -tm2);
    tm2 = tm1;
    tm1 = tn;
    y += gelu_exact(tn);
  }
  out[b] = y;
}

extern "C" void kernel_launch(void* const* d_in, const int* in_sizes, int n_in,
                              void* d_out, int out_size, void* d_ws, size_t ws_size,
                              hipStream_t stream) {
  const float* x   = (const float*)d_in[0];
  const float* Bm  = (const float*)d_in[1];
  const float* W0  = (const float*)d_in[2];
  const float* tW0 = (const float*)d_in[3];
  const float* W1  = (const float*)d_in[4];
  const float* tW1 = (const float*)d_in[5];
  const float* W2  = (const float*)d_in[6];
  const float* tW2 = (const float*)d_in[7];
  const float* W3  = (const float*)d_in[8];
  const float* tW3 = (const float*)d_in[9];
  const float* W4  = (const float*)d_in[10];
  const float* tW4 = (const float*)d_in[11];
  float* wf = (float*)d_ws;

  fuse_w<<<(SZ0 + 255) / 256, 256, 0, stream>>>(W0, tW0, wf + OFF0, 64, 128, SZ0);
  fuse_w<<<(SZ1 + 255) / 256, 256, 0, stream>>>(W1, tW1, wf + OFF1, 128, 128, SZ1);
  fuse_w<<<(SZ1 + 255) / 256, 256, 0, stream>>>(W2, tW2, wf + OFF2, 128, 128, SZ1);
  fuse_w<<<(SZ1 + 255) / 256, 256, 0, stream>>>(W3, tW3, wf + OFF3, 128, 128, SZ1);
  fuse_w<<<(SZ4 + 255) / 256, 256, 0, stream>>>(W4, tW4, wf + OFF4, 128, 1, SZ4);

  kan_main<<<(131072 + TPB - 1) / TPB, TPB, 0, stream>>>(x, Bm, wf, (float*)d_out);
}